// Round 3
// baseline (218.583 us; speedup 1.0000x reference)
//
#include <hip/hip_runtime.h>
#include <hip/hip_bf16.h>

// Problem constants (setup_inputs is fixed): B=4, C=32. N derived at runtime.
#define BB 4
#define CC 32

#define KMAX   512      // max 256-node buckets (N <= 131072 => src fits 17 bits)
#define STRIDE 4608     // staged capacity per bucket (mean 4096 + 8 sigma)

typedef float v2f __attribute__((ext_vector_type(2)));
typedef float v4f __attribute__((ext_vector_type(4)));

// ---- bf16 pack (RNE): uint = (lo bf16 | hi bf16 << 16) ----
__device__ __forceinline__ unsigned pack_bf2(float x, float y) {
    unsigned bx = __float_as_uint(x); bx += 0x7fffu + ((bx >> 16) & 1u);
    unsigned by = __float_as_uint(y); by += 0x7fffu + ((by >> 16) & 1u);
    return (bx >> 16) | (by & 0xffff0000u);
}

// Unpack uint4 (8 bf16) and accumulate into 4 float2 accumulators.
// float2 add compiles to v_pk_add_f32 on gfx950: 3 VALU/uint instead of 4.
__device__ __forceinline__ void acc_bf8(v2f* acc, uint4 v) {
    const unsigned* u = (const unsigned*)&v;
    #pragma unroll
    for (int k = 0; k < 4; ++k) {
        v2f t;
        t.x = __uint_as_float(u[k] << 16);
        t.y = __uint_as_float(u[k] & 0xffff0000u);
        acc[k] += t;
    }
}

// ======================================================== FAST PATH (R12)
// Phase A (fused): build blocks bin edges by dst>>8 into staged[] via LDS
// atomics + ~77k global reservation atomics. Extra blocks compute
// diff = pred - target in bf16, node-major 256 B records (NT input loads:
// pred/target are streamed exactly once).
__global__ __launch_bounds__(1024) void prep_a(
        const float* __restrict__ pred, const float* __restrict__ target,
        const int* __restrict__ edge_src, const int* __restrict__ edge_dst,
        int* __restrict__ bucketCursor, unsigned* __restrict__ staged,
        unsigned* __restrict__ diffu, float* __restrict__ outz,
        int N, int E, int buildBlocks, int K) {
    if (blockIdx.x == 0 && threadIdx.x == 0) *outz = 0.0f;  // for fused reduce
    if ((int)blockIdx.x < buildBlocks) {
        __shared__ int cnt[KMAX];
        __shared__ int base[KMAX];
        for (int k = threadIdx.x; k < K; k += 1024) cnt[k] = 0;
        __syncthreads();
        int e0 = blockIdx.x * 8192;              // 1024 threads x 8 edges
        unsigned w[8]; int rp[8];
        #pragma unroll
        for (int t = 0; t < 8; ++t) {
            int i = e0 + t * 1024 + threadIdx.x; // coalesced
            if (i < E) {
                int d = __builtin_nontemporal_load(&edge_dst[i]);
                int s = __builtin_nontemporal_load(&edge_src[i]);
                int bk = d >> 8;
                w[t] = (unsigned)s | ((unsigned)(d & 255) << 17);
                int r = atomicAdd(&cnt[bk], 1);  // LDS atomic (fast)
                rp[t] = r | (bk << 13);          // rank<8192, bk<512
            } else rp[t] = -1;
        }
        __syncthreads();
        for (int k = threadIdx.x; k < K; k += 1024) {
            int c = cnt[k];
            base[k] = c ? atomicAdd(&bucketCursor[k], c) : 0;  // global reserve
        }
        __syncthreads();
        #pragma unroll
        for (int t = 0; t < 8; ++t) {
            if (rp[t] >= 0) {
                int bk  = rp[t] >> 13;
                int pos = base[bk] + (rp[t] & 8191);
                if (pos < STRIDE)
                    staged[(size_t)bk * STRIDE + pos] = w[t];
            }
        }
    } else {
        int idx4 = ((int)blockIdx.x - buildBlocks) * 1024 + threadIdx.x;
        int total4 = N * CC;            // float4 count = BNC/4
        if (idx4 < total4) {
            int n8 = N * 8;
            int b  = idx4 / n8;
            int r  = idx4 - b * n8;
            int n  = r >> 3;
            const v4f p = __builtin_nontemporal_load((const v4f*)pred + idx4);
            const v4f t = __builtin_nontemporal_load((const v4f*)target + idx4);
            uint2 u;
            u.x = pack_bf2(p.x - t.x, p.y - t.y);
            u.y = pack_bf2(p.z - t.z, p.w - t.w);
            *(uint2*)(diffu + (size_t)n * 64 + b * 16 + ((r & 7) << 1)) = u;
        }
    }
}

// Fused bin+gather. Block = (bucket bk, sub-range of 64 nodes), 256 threads
// (R12: reverted from 512 — 8 blocks/CU gives finer scheduling quantum and
// more independent phase-1/phase-2 overlap across blocks; the 512-thr variant
// regressed 67->72 us). Plain bid mapping (XCD swizzle removed: gather
// sources are uniform-random over diffu, no per-XCD locality exists).
// Phase 1: stream the bucket's staged entries, keep those in our 64-node
// range, bin into a 16 KB LDS table (64 nodes x 64 slots) with LDS atomics.
// Phase 2: per node (16 per wave), read its edge list from LDS
// (conflict-free) and run the quarter-wave bf16 gather (4 edges/VMEM instr,
// 4 loads in flight), float2 (v_pk_add_f32) accumulation.
// Block result atomicAdd'ed into out (reduce kernel fused).
__global__ __launch_bounds__(256) void node_gather(
        const unsigned* __restrict__ diffu, const unsigned* __restrict__ staged,
        const int* __restrict__ bucketCursor, float* __restrict__ out,
        int N, float inv_count) {
    __shared__ int lists[64 * 64];   // 16 KB
    __shared__ int cnt[64];
    __shared__ float wpart[4];

    int bk  = blockIdx.x >> 2;
    int sub = blockIdx.x & 3;
    if (threadIdx.x < 64) cnt[threadIdx.x] = 0;
    __syncthreads();

    // ---- phase 1: bin our 64-node slice of bucket bk ----
    int count = min(bucketCursor[bk], STRIDE);
    const unsigned* sb = staged + (size_t)bk * STRIDE;
    for (int i = threadIdx.x; i < count; i += 256) {
        unsigned wv = sb[i];                     // coalesced
        int loc = (wv >> 17) & 255;
        if ((loc >> 6) == sub) {
            int l = loc & 63;
            int slot = atomicAdd(&cnt[l], 1);    // LDS atomic
            if (slot < 64) lists[(l << 6) + slot] = wv & 0x1ffff;
        }
    }
    __syncthreads();

    // ---- phase 2: gather 64 nodes, 16 per wave ----
    int wave = threadIdx.x >> 6;
    int lane = threadIdx.x & 63;
    int q  = lane >> 4;                          // edge-slot group 0..3
    int l4 = lane & 15;                          // 16 B slice of record
    const unsigned* base = diffu + l4 * 4;
    int node0 = (bk << 8) + (sub << 6);
    float total = 0.0f;                          // accumulated in lanes 0..15

    for (int t = 0; t < 16; ++t) {
        int l = (wave << 4) + t;
        int node = node0 + l;
        if (node >= N) break;
        int d = min(cnt[l], 64);                 // wave-uniform
        if (d == 0) continue;
        int cs = lists[(l << 6) + lane];         // conflict-free ds_read
        uint4 su = *(const uint4*)(base + (size_t)node * 64);  // self term

        v2f zero; zero.x = 0.0f; zero.y = 0.0f;
        v2f acc0[4], acc1[4];
        #pragma unroll
        for (int k = 0; k < 4; ++k) { acc0[k] = zero; acc1[k] = zero; }

        int j = 0;
        for (; j + 15 < d; j += 16) {            // 16 edges, 4 loads in flight
            int sA = __shfl(cs, j + q, 64);
            int sB = __shfl(cs, j + 4 + q, 64);
            int sC = __shfl(cs, j + 8 + q, 64);
            int sD = __shfl(cs, j + 12 + q, 64);
            uint4 vA = *(const uint4*)(base + (size_t)sA * 64);
            uint4 vB = *(const uint4*)(base + (size_t)sB * 64);
            uint4 vC = *(const uint4*)(base + (size_t)sC * 64);
            uint4 vD = *(const uint4*)(base + (size_t)sD * 64);
            acc_bf8(acc0, vA); acc_bf8(acc1, vB);
            acc_bf8(acc0, vC); acc_bf8(acc1, vD);
        }
        for (; j + 3 < d; j += 4) {              // 4 edges per iter
            int sA = __shfl(cs, j + q, 64);
            uint4 vA = *(const uint4*)(base + (size_t)sA * 64);
            acc_bf8(acc0, vA);
        }
        if (j < d) {                             // tail 1..3 edges
            int idx = j + q;
            int sA = __shfl(cs, idx < d ? idx : 0, 64);
            if (idx < d) {
                uint4 vA = *(const uint4*)(base + (size_t)sA * 64);
                acc_bf8(acc1, vA);
            }
        }
        // combine quarter groups: lanes l4, l4+16, l4+32, l4+48
        float inv = 1.0f / (float)d;
        const unsigned* sp = (const unsigned*)&su;
        #pragma unroll
        for (int k = 0; k < 4; ++k) {
            v2f v = acc0[k] + acc1[k];
            float vx = v.x, vy = v.y;
            vx += __shfl_down(vx, 32, 64);
            vx += __shfl_down(vx, 16, 64);
            vy += __shfl_down(vy, 32, 64);
            vy += __shfl_down(vy, 16, 64);
            if (lane < 16) {
                unsigned spk = sp[k];
                total += fabsf(__uint_as_float(spk << 16)         - vx * inv)
                       + fabsf(__uint_as_float(spk & 0xffff0000u) - vy * inv);
            }
        }
    }
    #pragma unroll
    for (int delta = 8; delta >= 1; delta >>= 1)  // lanes 0..15 carry values
        total += __shfl_down(total, delta, 64);
    if (lane == 0) wpart[wave] = total;
    __syncthreads();
    if (threadIdx.x == 0)
        atomicAdd(out, (wpart[0] + wpart[1] + wpart[2] + wpart[3]) * inv_count);
}

// ================================================================= REDUCE
// (fallback path only)
__global__ __launch_bounds__(256) void reduce_kernel(const float* __restrict__ partials, int n,
                                                     float* __restrict__ out, float inv_count) {
    float s = 0.0f;
    for (int i = threadIdx.x; i < n; i += 256) s += partials[i];
    int lane = threadIdx.x & 63;
    int wave = threadIdx.x >> 6;
    #pragma unroll
    for (int delta = 32; delta >= 1; delta >>= 1)
        s += __shfl_down(s, delta, 64);
    __shared__ float wpart[4];
    if (lane == 0) wpart[wave] = s;
    __syncthreads();
    if (threadIdx.x == 0)
        out[0] = (wpart[0] + wpart[1] + wpart[2] + wpart[3]) * inv_count;
}

// ==================================================== FALLBACK (R2) PATH
__global__ void build_kernel(const int* __restrict__ edge_src, const int* __restrict__ edge_dst,
                             int* __restrict__ deg, int* __restrict__ csr, int E) {
    int i = blockIdx.x * 256 + threadIdx.x;
    if (i < E) {
        int d = edge_dst[i];
        int slot = atomicAdd(&deg[d], 1);
        if (slot < 64) csr[(d << 6) + slot] = edge_src[i];
    }
}

__global__ __launch_bounds__(256) void node_kernel_pt(const float* __restrict__ pred,
                                                      const float* __restrict__ target,
                                                      const int* __restrict__ csr,
                                                      const int* __restrict__ deg,
                                                      float* __restrict__ partials, int N) {
    int wave = threadIdx.x >> 6;
    int lane = threadIdx.x & 63;
    int node = blockIdx.x * 4 + wave;
    float total = 0.0f;
    if (node < N) {
        int d = min(deg[node], 64);
        if (d > 0) {
            int o = node << 6;
            int cs = csr[o + lane];
            int b = (lane >> 3) & 3;
            int q = lane & 7;
            const float* arr = (lane >= 32) ? target : pred;
            int rowbase = b * N * CC + q * 4;
            float4 sp = *(const float4*)(pred + rowbase + node * CC);
            float4 st = *(const float4*)(target + rowbase + node * CC);
            float ax = 0.f, ay = 0.f, az = 0.f, aw = 0.f;
            for (int j = 0; j < d; ++j) {
                int s = __shfl(cs, j, 64);
                float4 v = *(const float4*)(arr + rowbase + s * CC);
                ax += v.x; ay += v.y; az += v.z; aw += v.w;
            }
            float dx = ax - __shfl_down(ax, 32, 64);
            float dy = ay - __shfl_down(ay, 32, 64);
            float dz = az - __shfl_down(az, 32, 64);
            float dw = aw - __shfl_down(aw, 32, 64);
            if (lane < 32) {
                float inv = 1.0f / (float)d;
                total = fabsf((sp.x - st.x) - dx * inv)
                      + fabsf((sp.y - st.y) - dy * inv)
                      + fabsf((sp.z - st.z) - dz * inv)
                      + fabsf((sp.w - st.w) - dw * inv);
            }
        }
    }
    #pragma unroll
    for (int delta = 32; delta >= 1; delta >>= 1)
        total += __shfl_down(total, delta, 64);
    __shared__ float wpart[4];
    if (lane == 0) wpart[wave] = total;
    __syncthreads();
    if (threadIdx.x == 0)
        partials[blockIdx.x] = wpart[0] + wpart[1] + wpart[2] + wpart[3];
}

extern "C" void kernel_launch(void* const* d_in, const int* in_sizes, int n_in,
                              void* d_out, int out_size, void* d_ws, size_t ws_size,
                              hipStream_t stream) {
    const float* pred   = (const float*)d_in[0];
    const float* target = (const float*)d_in[1];
    const int* edge_src = (const int*)d_in[2];
    const int* edge_dst = (const int*)d_in[3];
    float* out = (float*)d_out;

    const int BNC = in_sizes[0];
    const int E   = in_sizes[2];
    const int N   = BNC / (BB * CC);
    const int K   = (N + 255) >> 8;

    // fast-path layout (ints): cursor[512] | staged[K*STRIDE] | diffu[64N uints]
    size_t staged_off = 512;
    size_t diff_off   = staged_off + (size_t)K * STRIDE;
    diff_off = (diff_off + 3) & ~(size_t)3;          // 16 B align
    size_t fast_bytes = (diff_off + ((size_t)N << 6) + 16) * 4;

    if (ws_size >= fast_bytes && N <= 131072 && K <= KMAX) {
        int* cursor = (int*)d_ws;
        unsigned* staged = (unsigned*)((int*)d_ws + staged_off);
        unsigned* diffu = (unsigned*)((int*)d_ws + diff_off);

        hipMemsetAsync(cursor, 0, 512 * sizeof(int), stream);
        const int buildBlocks = (E + 8191) / 8192;              // 1024-thr blocks
        const int diffBlocks  = (N * CC + 1023) / 1024;
        prep_a<<<buildBlocks + diffBlocks, 1024, 0, stream>>>(
            pred, target, edge_src, edge_dst, cursor, staged, diffu, out,
            N, E, buildBlocks, K);
        node_gather<<<4 * K, 256, 0, stream>>>(diffu, staged, cursor, out, N,
                                               1.0f / (float)BNC);
    } else {
        // R2 fallback: deg[N] + csr[64N] + partials (reads pred/target directly)
        int* deg = (int*)d_ws;
        int* csr = deg + N;
        float* partials = (float*)(csr + ((size_t)N << 6));
        const int nblocks4 = (N + 3) / 4;

        hipMemsetAsync(deg, 0, (size_t)N * sizeof(int), stream);
        const int eblocks = (E + 255) / 256;
        build_kernel<<<eblocks, 256, 0, stream>>>(edge_src, edge_dst, deg, csr, E);
        node_kernel_pt<<<nblocks4, 256, 0, stream>>>(pred, target, csr, deg, partials, N);
        reduce_kernel<<<1, 256, 0, stream>>>(partials, nblocks4, out, 1.0f / (float)BNC);
    }
}

// Round 4
// 212.537 us; speedup vs baseline: 1.0284x; 1.0284x over previous
//
#include <hip/hip_runtime.h>
#include <hip/hip_bf16.h>

// Problem constants (setup_inputs is fixed): B=4, C=32. N derived at runtime.
#define BB 4
#define CC 32

#define KMAX   512      // max 256-node buckets (N <= 131072 => src fits 17 bits)
#define STRIDE 4608     // staged capacity per bucket (mean 4096 + 8 sigma)

// ---- bf16 pack (RNE): uint = (lo bf16 | hi bf16 << 16) ----
__device__ __forceinline__ unsigned pack_bf2(float x, float y) {
    unsigned bx = __float_as_uint(x); bx += 0x7fffu + ((bx >> 16) & 1u);
    unsigned by = __float_as_uint(y); by += 0x7fffu + ((by >> 16) & 1u);
    return (bx >> 16) | (by & 0xffff0000u);
}

// R0-proven scalar unpack+accumulate: 16 independent f32 chains across
// acc0/acc1 — keeps VALU filler available to hide memory latency.
// (R11/R12's v_pk_add_f32 variant LOWERED VALUBusy but RAISED duration:
// fewer dependency chains = less latency hiding. Do not re-introduce.)
__device__ __forceinline__ void acc_bf8(float* acc, uint4 v) {
    const unsigned* u = (const unsigned*)&v;
    #pragma unroll
    for (int k = 0; k < 4; ++k) {
        acc[2 * k]     += __uint_as_float(u[k] << 16);
        acc[2 * k + 1] += __uint_as_float(u[k] & 0xffff0000u);
    }
}

// ======================================================== FAST PATH (R13)
// Phase A (fused, exact R0): build blocks bin edges by dst>>8 into staged[]
// via LDS atomics + ~77k global reservation atomics. Extra blocks compute
// diff = pred - target in bf16, node-major 256 B records.
__global__ __launch_bounds__(1024) void prep_a(
        const float* __restrict__ pred, const float* __restrict__ target,
        const int* __restrict__ edge_src, const int* __restrict__ edge_dst,
        int* __restrict__ bucketCursor, unsigned* __restrict__ staged,
        unsigned* __restrict__ diffu, int N, int E, int buildBlocks, int K) {
    if ((int)blockIdx.x < buildBlocks) {
        __shared__ int cnt[KMAX];
        __shared__ int base[KMAX];
        for (int k = threadIdx.x; k < K; k += 1024) cnt[k] = 0;
        __syncthreads();
        int e0 = blockIdx.x * 8192;              // 1024 threads x 8 edges
        unsigned w[8]; int rp[8];
        #pragma unroll
        for (int t = 0; t < 8; ++t) {
            int i = e0 + t * 1024 + threadIdx.x; // coalesced
            if (i < E) {
                int d = __builtin_nontemporal_load(&edge_dst[i]);
                int s = __builtin_nontemporal_load(&edge_src[i]);
                int bk = d >> 8;
                w[t] = (unsigned)s | ((unsigned)(d & 255) << 17);
                int r = atomicAdd(&cnt[bk], 1);  // LDS atomic (fast)
                rp[t] = r | (bk << 13);          // rank<8192, bk<512
            } else rp[t] = -1;
        }
        __syncthreads();
        for (int k = threadIdx.x; k < K; k += 1024) {
            int c = cnt[k];
            base[k] = c ? atomicAdd(&bucketCursor[k], c) : 0;  // global reserve
        }
        __syncthreads();
        #pragma unroll
        for (int t = 0; t < 8; ++t) {
            if (rp[t] >= 0) {
                int bk  = rp[t] >> 13;
                int pos = base[bk] + (rp[t] & 8191);
                if (pos < STRIDE)
                    staged[(size_t)bk * STRIDE + pos] = w[t];
            }
        }
    } else {
        int idx4 = ((int)blockIdx.x - buildBlocks) * 1024 + threadIdx.x;
        int total4 = N * CC;            // float4 count = BNC/4
        if (idx4 < total4) {
            int n8 = N * 8;
            int b  = idx4 / n8;
            int r  = idx4 - b * n8;
            int n  = r >> 3;
            const float4 p = *(const float4*)(pred   + ((size_t)idx4 << 2));
            const float4 t = *(const float4*)(target + ((size_t)idx4 << 2));
            uint2 u;
            u.x = pack_bf2(p.x - t.x, p.y - t.y);
            u.y = pack_bf2(p.z - t.z, p.w - t.w);
            *(uint2*)(diffu + (size_t)n * 64 + b * 16 + ((r & 7) << 1)) = u;
        }
    }
}

// Fused bin+gather (R0 structure: 256 thr, 4 waves x 16 nodes, partials +
// separate reduce). R13's ONE change: the edge loop is a single uniform
// 16-edge-granule loop with clamped shuffle indices and per-q-group
// predicated accumulation — 4 loads in flight on EVERY round, including
// partial ones. R0 dropped to 1 load in flight for the d<16 nodes (~47%)
// and for remainders, exposing ~2.7 serial memory rounds per node vs ~1.4.
// Clamp duplicates re-read record d-1 (just fetched -> L1 hit, no HBM cost).
__global__ __launch_bounds__(256) void node_gather(
        const unsigned* __restrict__ diffu, const unsigned* __restrict__ staged,
        const int* __restrict__ bucketCursor, float* __restrict__ partials, int N) {
    __shared__ int lists[64 * 64];   // 16 KB
    __shared__ int cnt[64];
    __shared__ float wpart[4];

    int bk  = blockIdx.x >> 2;
    int sub = blockIdx.x & 3;
    if (threadIdx.x < 64) cnt[threadIdx.x] = 0;
    __syncthreads();

    // ---- phase 1: bin our 64-node slice of bucket bk ----
    int count = min(bucketCursor[bk], STRIDE);
    const unsigned* sb = staged + (size_t)bk * STRIDE;
    for (int i = threadIdx.x; i < count; i += 256) {
        unsigned wv = sb[i];                     // coalesced
        int loc = (wv >> 17) & 255;
        if ((loc >> 6) == sub) {
            int l = loc & 63;
            int slot = atomicAdd(&cnt[l], 1);    // LDS atomic
            if (slot < 64) lists[(l << 6) + slot] = wv & 0x1ffff;
        }
    }
    __syncthreads();

    // ---- phase 2: gather 64 nodes, 16 per wave ----
    int wave = threadIdx.x >> 6;
    int lane = threadIdx.x & 63;
    int q  = lane >> 4;                          // edge-slot group 0..3
    int l4 = lane & 15;                          // 16 B slice of record
    const unsigned* base = diffu + l4 * 4;
    int node0 = (bk << 8) + (sub << 6);
    float total = 0.0f;                          // accumulated in lanes 0..15

    for (int t = 0; t < 16; ++t) {
        int l = (wave << 4) + t;
        int node = node0 + l;
        if (node >= N) break;
        int d = min(cnt[l], 64);                 // wave-uniform
        if (d == 0) continue;
        int cs = lists[(l << 6) + lane];         // conflict-free ds_read
        uint4 su = *(const uint4*)(base + (size_t)node * 64);  // self term

        float acc0[8], acc1[8];
        #pragma unroll
        for (int k = 0; k < 8; ++k) { acc0[k] = 0.f; acc1[k] = 0.f; }

        int dm1 = d - 1;
        for (int j = 0; j < d; j += 16) {        // uniform: 4 loads in flight
            int iA = j + q;
            int iB = j + 4 + q;
            int iC = j + 8 + q;
            int iD = j + 12 + q;
            int sA = __shfl(cs, min(iA, dm1), 64);
            int sB = __shfl(cs, min(iB, dm1), 64);
            int sC = __shfl(cs, min(iC, dm1), 64);
            int sD = __shfl(cs, min(iD, dm1), 64);
            uint4 vA = *(const uint4*)(base + (size_t)sA * 64);
            uint4 vB = *(const uint4*)(base + (size_t)sB * 64);
            uint4 vC = *(const uint4*)(base + (size_t)sC * 64);
            uint4 vD = *(const uint4*)(base + (size_t)sD * 64);
            if (iA < d) acc_bf8(acc0, vA);       // exec-masked per q-group
            if (iB < d) acc_bf8(acc1, vB);
            if (iC < d) acc_bf8(acc0, vC);
            if (iD < d) acc_bf8(acc1, vD);
        }

        // combine quarter groups: lanes l4, l4+16, l4+32, l4+48
        float inv = 1.0f / (float)d;
        const unsigned* sp = (const unsigned*)&su;
        #pragma unroll
        for (int k = 0; k < 8; ++k) {
            float v = acc0[k] + acc1[k];
            v += __shfl_down(v, 32, 64);
            v += __shfl_down(v, 16, 64);
            if (lane < 16) {
                unsigned spk = sp[k >> 1];
                float s = (k & 1) ? __uint_as_float(spk & 0xffff0000u)
                                  : __uint_as_float(spk << 16);
                total += fabsf(s - v * inv);
            }
        }
    }
    #pragma unroll
    for (int delta = 8; delta >= 1; delta >>= 1)  // lanes 0..15 carry values
        total += __shfl_down(total, delta, 64);
    if (lane == 0) wpart[wave] = total;
    __syncthreads();
    if (threadIdx.x == 0)
        partials[blockIdx.x] = wpart[0] + wpart[1] + wpart[2] + wpart[3];
}

// ================================================================= REDUCE
__global__ __launch_bounds__(256) void reduce_kernel(const float* __restrict__ partials, int n,
                                                     float* __restrict__ out, float inv_count) {
    float s = 0.0f;
    for (int i = threadIdx.x; i < n; i += 256) s += partials[i];
    int lane = threadIdx.x & 63;
    int wave = threadIdx.x >> 6;
    #pragma unroll
    for (int delta = 32; delta >= 1; delta >>= 1)
        s += __shfl_down(s, delta, 64);
    __shared__ float wpart[4];
    if (lane == 0) wpart[wave] = s;
    __syncthreads();
    if (threadIdx.x == 0)
        out[0] = (wpart[0] + wpart[1] + wpart[2] + wpart[3]) * inv_count;
}

// ==================================================== FALLBACK (R2) PATH
__global__ void build_kernel(const int* __restrict__ edge_src, const int* __restrict__ edge_dst,
                             int* __restrict__ deg, int* __restrict__ csr, int E) {
    int i = blockIdx.x * 256 + threadIdx.x;
    if (i < E) {
        int d = edge_dst[i];
        int slot = atomicAdd(&deg[d], 1);
        if (slot < 64) csr[(d << 6) + slot] = edge_src[i];
    }
}

__global__ __launch_bounds__(256) void node_kernel_pt(const float* __restrict__ pred,
                                                      const float* __restrict__ target,
                                                      const int* __restrict__ csr,
                                                      const int* __restrict__ deg,
                                                      float* __restrict__ partials, int N) {
    int wave = threadIdx.x >> 6;
    int lane = threadIdx.x & 63;
    int node = blockIdx.x * 4 + wave;
    float total = 0.0f;
    if (node < N) {
        int d = min(deg[node], 64);
        if (d > 0) {
            int o = node << 6;
            int cs = csr[o + lane];
            int b = (lane >> 3) & 3;
            int q = lane & 7;
            const float* arr = (lane >= 32) ? target : pred;
            int rowbase = b * N * CC + q * 4;
            float4 sp = *(const float4*)(pred + rowbase + node * CC);
            float4 st = *(const float4*)(target + rowbase + node * CC);
            float ax = 0.f, ay = 0.f, az = 0.f, aw = 0.f;
            for (int j = 0; j < d; ++j) {
                int s = __shfl(cs, j, 64);
                float4 v = *(const float4*)(arr + rowbase + s * CC);
                ax += v.x; ay += v.y; az += v.z; aw += v.w;
            }
            float dx = ax - __shfl_down(ax, 32, 64);
            float dy = ay - __shfl_down(ay, 32, 64);
            float dz = az - __shfl_down(az, 32, 64);
            float dw = aw - __shfl_down(aw, 32, 64);
            if (lane < 32) {
                float inv = 1.0f / (float)d;
                total = fabsf((sp.x - st.x) - dx * inv)
                      + fabsf((sp.y - st.y) - dy * inv)
                      + fabsf((sp.z - st.z) - dz * inv)
                      + fabsf((sp.w - st.w) - dw * inv);
            }
        }
    }
    #pragma unroll
    for (int delta = 32; delta >= 1; delta >>= 1)
        total += __shfl_down(total, delta, 64);
    __shared__ float wpart[4];
    if (lane == 0) wpart[wave] = total;
    __syncthreads();
    if (threadIdx.x == 0)
        partials[blockIdx.x] = wpart[0] + wpart[1] + wpart[2] + wpart[3];
}

extern "C" void kernel_launch(void* const* d_in, const int* in_sizes, int n_in,
                              void* d_out, int out_size, void* d_ws, size_t ws_size,
                              hipStream_t stream) {
    const float* pred   = (const float*)d_in[0];
    const float* target = (const float*)d_in[1];
    const int* edge_src = (const int*)d_in[2];
    const int* edge_dst = (const int*)d_in[3];
    float* out = (float*)d_out;

    const int BNC = in_sizes[0];
    const int E   = in_sizes[2];
    const int N   = BNC / (BB * CC);
    const int K   = (N + 255) >> 8;

    // fast-path layout (ints): cursor[512] | staged[K*STRIDE] |
    //                          diffu[64N uints] | partials[4K]
    size_t staged_off = 512;
    size_t diff_off   = staged_off + (size_t)K * STRIDE;
    diff_off = (diff_off + 3) & ~(size_t)3;          // 16 B align
    size_t part_off   = diff_off + ((size_t)N << 6);
    size_t fast_bytes = (part_off + (size_t)4 * K + 16) * 4;

    if (ws_size >= fast_bytes && N <= 131072 && K <= KMAX) {
        int* cursor = (int*)d_ws;
        unsigned* staged = (unsigned*)((int*)d_ws + staged_off);
        unsigned* diffu = (unsigned*)((int*)d_ws + diff_off);
        float* partials = (float*)((int*)d_ws + part_off);

        hipMemsetAsync(cursor, 0, 512 * sizeof(int), stream);
        const int buildBlocks = (E + 8191) / 8192;              // 1024-thr blocks
        const int diffBlocks  = (N * CC + 1023) / 1024;
        prep_a<<<buildBlocks + diffBlocks, 1024, 0, stream>>>(
            pred, target, edge_src, edge_dst, cursor, staged, diffu,
            N, E, buildBlocks, K);
        node_gather<<<4 * K, 256, 0, stream>>>(diffu, staged, cursor, partials, N);
        reduce_kernel<<<1, 256, 0, stream>>>(partials, 4 * K, out, 1.0f / (float)BNC);
    } else {
        // R2 fallback: deg[N] + csr[64N] + partials (reads pred/target directly)
        int* deg = (int*)d_ws;
        int* csr = deg + N;
        float* partials = (float*)(csr + ((size_t)N << 6));
        const int nblocks4 = (N + 3) / 4;

        hipMemsetAsync(deg, 0, (size_t)N * sizeof(int), stream);
        const int eblocks = (E + 255) / 256;
        build_kernel<<<eblocks, 256, 0, stream>>>(edge_src, edge_dst, deg, csr, E);
        node_kernel_pt<<<nblocks4, 256, 0, stream>>>(pred, target, csr, deg, partials, N);
        reduce_kernel<<<1, 256, 0, stream>>>(partials, nblocks4, out, 1.0f / (float)BNC);
    }
}